// Round 13
// baseline (303.043 us; speedup 1.0000x reference)
//
#include <hip/hip_runtime.h>
#include <hip/hip_bf16.h>

#define BTOT 16384
typedef unsigned short u16;
typedef __attribute__((ext_vector_type(8))) short bf16x8;
typedef __attribute__((ext_vector_type(8))) unsigned short u16x8;
typedef __attribute__((ext_vector_type(4))) float f32x4;

#define MFMA16(a, b, c) __builtin_amdgcn_mfma_f32_16x16x32_bf16(a, b, c, 0, 0, 0)
#define NSLOT 16

__device__ __forceinline__ u16 f2b(float f) {
  unsigned int i = __float_as_uint(f);
  return (u16)((i + 0x7FFFu + ((i >> 16) & 1u)) >> 16);
}
__device__ __forceinline__ float b2f(u16 u) {
  return __uint_as_float(((unsigned int)u) << 16);
}
__device__ __forceinline__ unsigned pk2(float x, float y) {
  __hip_bfloat162 h = __float22bfloat162_rn(make_float2(x, y));
  unsigned r; __builtin_memcpy(&r, &h, 4); return r;
}
__device__ __forceinline__ bf16x8 pack8(float4 lo, float4 hi) {
  union { unsigned u[4]; bf16x8 v; } r;
  r.u[0] = pk2(lo.x, lo.y); r.u[1] = pk2(lo.z, lo.w);
  r.u[2] = pk2(hi.x, hi.y); r.u[3] = pk2(hi.z, hi.w);
  return r.v;
}

__device__ const int c_mb[8][3]  = {{0,0,0},{1,0,0},{1,0,0},{1,0,0},{1,0,0},{1,0,0},{1,0,0},{1,1,0}};
__device__ const int c_mj[8][3]  = {{0,1,5},{0,3,7},{5,7,8},{1,2,0},{3,4,0},{8,9,0},{10,11,0},{6,7,10}};
__device__ const int c_opof[8]   = {0,1,1,2,2,2,2,3};
__device__ const int c_jmap[12]  = {0,1,3,4,8,9,2,7,5,6,10,11};
__device__ const int c_vj[4]     = {2,4,9,11};

// ---------------- prep: W -> bf16 in B-FRAGMENT order --------------------------------
// Element (n=d, k): c=k>>6, kt=(k>>5)&1, kg=(k>>3)&3, ko=k&7, nblk=n>>4, nl=n&15.
// dest = base + c*8192 + nblk*1024 + kt*512 + (kg*16 + nl)*8 + ko.
// Lane l of a wave reading 16B at (c,nblk,kt, l*8) gets exactly its MFMA B-fragment:
// n = nblk*16 + (l&15), k = c*64 + kt*32 + (l>>4)*8 .. +7. 1KB/wave, fully coalesced.
// W_ve K-halves swapped (k^128) so both stage1 passes use X = [eout | mix].
__global__ __launch_bounds__(256) void k_prep(
    const float* __restrict__ wev, const float* __restrict__ wve,
    const float* __restrict__ w1, const float* __restrict__ w2,
    const float* __restrict__ w3, const float* __restrict__ w4,
    u16* __restrict__ wb, float* __restrict__ stats)
{
  int id = blockIdx.x * 256 + threadIdx.x;
  if (blockIdx.x == 0) {
    for (int i = threadIdx.x; i < NSLOT * 1536; i += 256) stats[i] = 0.f;
  }
  const float* src; int base, K, local;
  if (id < 32768)       { src = wev; base = 0;      K = 256; local = id; }
  else if (id < 65536)  { src = wve; base = 32768;  K = 256; local = id - 32768; }
  else if (id < 114688) { src = w1;  base = 65536;  K = 384; local = id - 65536; }
  else if (id < 163840) { src = w2;  base = 114688; K = 384; local = id - 114688; }
  else if (id < 196608) { src = w3;  base = 163840; K = 256; local = id - 163840; }
  else if (id < 245760) { src = w4;  base = 196608; K = 384; local = id - 196608; }
  else return;
  int d = local / K, k = local - d * K;
  int dk = (base == 32768) ? (k ^ 128) : k;
  int c = dk >> 6, kt = (dk >> 5) & 1, kg = (dk >> 3) & 3, ko = dk & 7;
  int dest = base + c * 8192 + (d >> 4) * 1024 + kt * 512 + ((kg << 4) + (d & 15)) * 8 + ko;
  wb[dest] = f2b(src[local]);
}

// ---------------- stage1: B-from-global-regs, barrier-free K-loop, 3 blocks/CU -----
// 256 thr = 4 waves (2M x 2N); 8 batches -> M=96, N=128, K=256 per matrix.
__global__ __launch_bounds__(256, 3) void k_stage1(
    const float* __restrict__ gout, const float* __restrict__ eout,
    const float* __restrict__ evs, const float* __restrict__ ves,
    const u16* __restrict__ wb_ev, const u16* __restrict__ wb_ve,
    u16* __restrict__ y_ev, u16* __restrict__ y_ve, float* __restrict__ stats)
{
  __shared__ __align__(16) char lds[49152];
  __shared__ float s_red[512];
  char* se = lds;                 // 96x128 bf16 eout (swizzled 256B rows); VE dump
  char* sm = lds + 24576;         // mix (ev then ve); EV dump

  const int tid = threadIdx.x;
  const int l = tid & 63, wv = tid >> 6;
  const int wm = wv >> 1, wn = wv & 1;
  const int b0 = blockIdx.x * 8;
  const int kq = (l >> 4) * 8;
  const int bb = tid >> 5;
  const int d4 = (tid & 31) * 4;

  // ---- fused prologue: stage eout -> se + compute ev mix -> sm ----
  {
    float mev[12][4];
    #pragma unroll
    for (int n = 0; n < 12; ++n)
      #pragma unroll
      for (int q = 0; q < 4; ++q) mev[n][q] = 0.f;
    #pragma unroll
    for (int j = 0; j < 12; ++j) {
      float4 g4 = *(const float4*)&gout[((size_t)(b0 + bb) * 12 + j) * 128 + d4];
      float4 e4 = *(const float4*)&eout[((size_t)(b0 + bb) * 12 + j) * 128 + d4];
      int row = bb * 12 + j;
      uint2 ep = make_uint2(pk2(e4.x, e4.y), pk2(e4.z, e4.w));
      *(uint2*)(se + row * 256 + ((d4 * 2) ^ ((row & 7) << 4))) = ep;
      #pragma unroll
      for (int n = 0; n < 12; ++n) {
        float w = evs[n * 12 + j];   // uniform scalar load (K$)
        mev[n][0] = fmaf(w, g4.x, mev[n][0]); mev[n][1] = fmaf(w, g4.y, mev[n][1]);
        mev[n][2] = fmaf(w, g4.z, mev[n][2]); mev[n][3] = fmaf(w, g4.w, mev[n][3]);
      }
    }
    #pragma unroll
    for (int n = 0; n < 12; ++n) {
      int row = bb * 12 + n;
      uint2 mp = make_uint2(pk2(mev[n][0], mev[n][1]), pk2(mev[n][2], mev[n][3]));
      *(uint2*)(sm + row * 256 + ((d4 * 2) ^ ((row & 7) << 4))) = mp;
    }
  }

  float sE[4] = {0,0,0,0}, qE[4] = {0,0,0,0}, sV[4] = {0,0,0,0}, qV[4] = {0,0,0,0};

  auto run_pass = [&](const u16* wmat, u16* yout, char* dump, float* sS, float* qS) {
    f32x4 acc[3][4];
    #pragma unroll
    for (int mi = 0; mi < 3; ++mi)
      #pragma unroll
      for (int ni = 0; ni < 4; ++ni) acc[mi][ni] = (f32x4){0.f, 0.f, 0.f, 0.f};

    __syncthreads();   // X buffers (se/sm) fully written before any wave reads
    #pragma unroll
    for (int c = 0; c < 4; ++c) {
      const char* xb = (c < 2) ? se : sm;
      #pragma unroll
      for (int kt = 0; kt < 2; ++kt) {
        bf16x8 a[3], bq[4];
        const u16* wp = wmat + c * 8192 + kt * 512 + l * 8;
        #pragma unroll
        for (int ni = 0; ni < 4; ++ni)
          bq[ni] = *(const bf16x8*)&wp[(wn * 4 + ni) * 1024];   // coalesced 1KB/wave
        const int kb = (((c & 1) * 64 + kt * 32 + kq)) * 2;
        #pragma unroll
        for (int mi = 0; mi < 3; ++mi) {
          int row = (wm * 3 + mi) * 16 + (l & 15);
          a[mi] = *(const bf16x8*)(xb + row * 256 + (kb ^ ((row & 7) << 4)));
        }
        #pragma unroll
        for (int mi = 0; mi < 3; ++mi)
          #pragma unroll
          for (int ni = 0; ni < 4; ++ni)
            acc[mi][ni] = MFMA16(a[mi], bq[ni], acc[mi][ni]);
      }
    }
    __syncthreads();   // all waves done reading se/sm before dump overwrite
    // epilogue: stats + bf16 dump to LDS + coalesced store
    #pragma unroll
    for (int mi = 0; mi < 3; ++mi)
      #pragma unroll
      for (int ni = 0; ni < 4; ++ni)
        #pragma unroll
        for (int q = 0; q < 4; ++q) {
          float v = acc[mi][ni][q];
          sS[ni] += v; qS[ni] += v * v;
          int row = (wm * 3 + mi) * 16 + (l >> 4) * 4 + q;
          int cb = ((wn * 4 + ni) * 16 + (l & 15)) * 2;
          *(u16*)(dump + row * 256 + (cb ^ ((row & 7) << 4))) = f2b(v);
        }
    __syncthreads();
    #pragma unroll
    for (int q = 0; q < 6; ++q) {
      int i = tid + q * 256;
      int row = i >> 4, cb = (i & 15) * 16;
      u16x8 v = *(const u16x8*)(dump + row * 256 + (cb ^ ((row & 7) << 4)));
      *(u16x8*)&yout[(size_t)(b0 * 12 + row) * 128 + (i & 15) * 8] = v;
    }
    __syncthreads();   // store done before dump-buffer reuse (mix_ve / s_red phase)
  };

  // EV: chunks 0,1 read se, 2,3 read sm(mix_ev); dump into sm (consumed)
  run_pass(wb_ev, y_ev, sm, sE, qE);

  // mix_ve -> sm (gout re-read, L2/L3-hot); run_pass-entry barrier orders readers
  {
    float mve[12][4];
    #pragma unroll
    for (int n = 0; n < 12; ++n)
      #pragma unroll
      for (int q = 0; q < 4; ++q) mve[n][q] = 0.f;
    #pragma unroll
    for (int j = 0; j < 12; ++j) {
      float4 g4 = *(const float4*)&gout[((size_t)(b0 + bb) * 12 + j) * 128 + d4];
      #pragma unroll
      for (int n = 0; n < 12; ++n) {
        float w = ves[n * 12 + j];   // uniform scalar load
        mve[n][0] = fmaf(w, g4.x, mve[n][0]); mve[n][1] = fmaf(w, g4.y, mve[n][1]);
        mve[n][2] = fmaf(w, g4.z, mve[n][2]); mve[n][3] = fmaf(w, g4.w, mve[n][3]);
      }
    }
    #pragma unroll
    for (int n = 0; n < 12; ++n) {
      int row = bb * 12 + n;
      uint2 mp = make_uint2(pk2(mve[n][0], mve[n][1]), pk2(mve[n][2], mve[n][3]));
      *(uint2*)(sm + row * 256 + ((d4 * 2) ^ ((row & 7) << 4))) = mp;
    }
  }

  // VE: chunks 0,1 read se (W_ve halves pre-swapped), 2,3 read sm(mix_ve); dump se
  run_pass(wb_ve, y_ve, se, sV, qV);

  // stats finale
  s_red[tid] = 0.f; s_red[tid + 256] = 0.f;
  __syncthreads();
  #pragma unroll
  for (int ni = 0; ni < 4; ++ni) {
    float a1 = sE[ni], b1 = qE[ni], a2 = sV[ni], b2 = qV[ni];
    a1 += __shfl_xor(a1, 16); a1 += __shfl_xor(a1, 32);
    b1 += __shfl_xor(b1, 16); b1 += __shfl_xor(b1, 32);
    a2 += __shfl_xor(a2, 16); a2 += __shfl_xor(a2, 32);
    b2 += __shfl_xor(b2, 16); b2 += __shfl_xor(b2, 32);
    if (l < 16) {
      int ch = (wn * 4 + ni) * 16 + l;
      atomicAdd(&s_red[ch], a1);       atomicAdd(&s_red[128 + ch], b1);
      atomicAdd(&s_red[256 + ch], a2); atomicAdd(&s_red[384 + ch], b2);
    }
  }
  __syncthreads();
  const int sb = (blockIdx.x & (NSLOT - 1)) * 1536;   // slot-spread atomics
  atomicAdd(&stats[sb + tid], s_red[tid]);
  atomicAdd(&stats[sb + 256 + tid], s_red[256 + tid]);
}

// ---------------- fin1: sum slots -> BN affine for ev/ve ---------------------------
__global__ void k_fin1(const float* __restrict__ stats, float* __restrict__ scale,
                       const float* __restrict__ gev, const float* __restrict__ bev,
                       const float* __restrict__ gve, const float* __restrict__ bve)
{
  int t = threadIdx.x;
  int m = t >> 7, d = t & 127;
  float s = 0.f, q = 0.f;
  #pragma unroll
  for (int sl = 0; sl < NSLOT; ++sl) {
    s += stats[sl * 1536 + m * 256 + d];
    q += stats[sl * 1536 + m * 256 + 128 + d];
  }
  float cnt = (float)(BTOT * 12);
  float mean = s / cnt, var = q / cnt - mean * mean;
  float rs = rsqrtf(var + 1e-5f);
  float g = m ? gve[d] : gev[d];
  float b = m ? bve[d] : bev[d];
  float a = g * rs;
  scale[m * 256 + d] = a;
  scale[m * 256 + 128 + d] = b - mean * a;
}

// ---------------- stage2: B-from-global-regs, barrier-free K-loop ------------------
// 4096 blocks: r = bid&7, 32 batches; 4 waves (mw x nw); M=32, N=128, K=256/384
__global__ __launch_bounds__(256, 4) void k_stage2(
    const u16* __restrict__ y_ev, const u16* __restrict__ y_ve,
    const float* __restrict__ scale,
    const u16* __restrict__ wb1, const u16* __restrict__ wb2,
    const u16* __restrict__ wb3, const u16* __restrict__ wb4,
    u16* __restrict__ y_op, float* __restrict__ stats)
{
  __shared__ __align__(16) u16 s_d[32 * 128];
  __shared__ float s_scale[512];
  __shared__ float s_red[256];
  char* sd = (char*)s_d;

  const int tid = threadIdx.x, l = tid & 63, wv = tid >> 6;
  const int mw = wv & 1, nw = wv >> 1;
  const int r = blockIdx.x & 7;
  const int b0 = (blockIdx.x >> 3) * 32;
  const int Kr = (r >= 3 && r <= 6) ? 256 : 384;
  const u16* wr = (r == 0) ? wb1 : (r <= 2) ? wb2 : (r <= 6) ? wb3 : wb4;
  const int o = c_opof[r];
  const int j0 = c_mj[r][0], j1 = c_mj[r][1], j2 = c_mj[r][2];
  const int m0 = c_mb[r][0], m1 = c_mb[r][1], m2 = c_mb[r][2];

  for (int i = tid; i < 512; i += 256) s_scale[i] = scale[i];
  s_red[tid] = 0.f;
  __syncthreads();   // s_scale read by all threads below

  f32x4 acc[4];
  #pragma unroll
  for (int ni = 0; ni < 4; ++ni) acc[ni] = (f32x4){0.f, 0.f, 0.f, 0.f};

  const int nch = Kr >> 6;
  const int kq = (l >> 4) * 8;
  const int batch = b0 + mw * 16 + (l & 15);

  for (int c = 0; c < nch; ++c) {
    const int s = c >> 1;
    const int j = (s == 0) ? j0 : (s == 1) ? j1 : j2;
    const int mb = (s == 0) ? m0 : (s == 1) ? m1 : m2;
    const int sb = mb ? 256 : 0;
    const u16* ys = mb ? y_ve : y_ev;
    #pragma unroll
    for (int kt = 0; kt < 2; ++kt) {
      const int chan = (c & 1) * 64 + kt * 32 + kq;
      u16x8 u = *(const u16x8*)&ys[((size_t)batch * 12 + j) * 128 + chan];
      float4 a0 = *(const float4*)&s_scale[sb + chan];
      float4 a1 = *(const float4*)&s_scale[sb + chan + 4];
      float4 c0 = *(const float4*)&s_scale[sb + 128 + chan];
      float4 c1 = *(const float4*)&s_scale[sb + 128 + chan + 4];
      float4 lo, hi;
      lo.x = fmaxf(fmaf(b2f(u[0]), a0.x, c0.x), 0.f);
      lo.y = fmaxf(fmaf(b2f(u[1]), a0.y, c0.y), 0.f);
      lo.z = fmaxf(fmaf(b2f(u[2]), a0.z, c0.z), 0.f);
      lo.w = fmaxf(fmaf(b2f(u[3]), a0.w, c0.w), 0.f);
      hi.x = fmaxf(fmaf(b2f(u[4]), a1.x, c1.x), 0.f);
      hi.y = fmaxf(fmaf(b2f(u[5]), a1.y, c1.y), 0.f);
      hi.z = fmaxf(fmaf(b2f(u[6]), a1.z, c1.z), 0.f);
      hi.w = fmaxf(fmaf(b2f(u[7]), a1.w, c1.w), 0.f);
      bf16x8 afrag = pack8(lo, hi);
      const u16* wp = wr + c * 8192 + kt * 512 + l * 8;
      #pragma unroll
      for (int ni = 0; ni < 4; ++ni) {
        bf16x8 b = *(const bf16x8*)&wp[(nw * 4 + ni) * 1024];   // coalesced
        acc[ni] = MFMA16(afrag, b, acc[ni]);
      }
    }
  }
  __syncthreads();   // (s_d unused before; barrier orders s_red zero vs adds below)

  #pragma unroll
  for (int ni = 0; ni < 4; ++ni) {
    float s1 = 0.f, q1 = 0.f;
    #pragma unroll
    for (int q = 0; q < 4; ++q) {
      float v = acc[ni][q];
      s1 += v; q1 += v * v;
      int row = mw * 16 + (l >> 4) * 4 + q;
      int cb = ((nw * 4 + ni) * 16 + (l & 15)) * 2;
      *(u16*)(sd + row * 256 + (cb ^ ((row & 7) << 4))) = f2b(v);
    }
    s1 += __shfl_xor(s1, 16); s1 += __shfl_xor(s1, 32);
    q1 += __shfl_xor(q1, 16); q1 += __shfl_xor(q1, 32);
    if (l < 16) {
      int ch = (nw * 4 + ni) * 16 + l;
      atomicAdd(&s_red[ch], s1);
      atomicAdd(&s_red[128 + ch], q1);
    }
  }
  __syncthreads();
  #pragma unroll
  for (int q = 0; q < 2; ++q) {
    int i = tid + q * 256;
    int row = i >> 4, cb = (i & 15) * 16;
    u16x8 v = *(const u16x8*)(sd + row * 256 + (cb ^ ((row & 7) << 4)));
    *(u16x8*)&y_op[((size_t)(b0 + row) * 8 + r) * 128 + (i & 15) * 8] = v;
  }
  const int sb2 = (blockIdx.x & (NSLOT - 1)) * 1536;
  atomicAdd(&stats[sb2 + 512 + o * 256 + tid], s_red[tid]);
}

// ---------------- fin2: sum slots -> BN affine for ops -----------------------------
__global__ void k_fin2(const float* __restrict__ stats, float* __restrict__ scale,
    const float* __restrict__ g1, const float* __restrict__ b1,
    const float* __restrict__ g2, const float* __restrict__ b2,
    const float* __restrict__ g3, const float* __restrict__ b3,
    const float* __restrict__ g4, const float* __restrict__ b4)
{
  int t = threadIdx.x; // 512
  int o = t >> 7, d = t & 127;
  float s = 0.f, q = 0.f;
  #pragma unroll
  for (int sl = 0; sl < NSLOT; ++sl) {
    s += stats[sl * 1536 + 512 + o * 256 + d];
    q += stats[sl * 1536 + 512 + o * 256 + 128 + d];
  }
  float cnt = (o == 0 || o == 3) ? 16384.f : (o == 1 ? 32768.f : 65536.f);
  float mean = s / cnt, var = q / cnt - mean * mean;
  float rs = rsqrtf(var + 1e-5f);
  const float* gp = (o == 0) ? g1 : (o == 1) ? g2 : (o == 2) ? g3 : g4;
  const float* bp = (o == 0) ? b1 : (o == 1) ? b2 : (o == 2) ? b3 : b4;
  float a = gp[d] * rs;
  scale[512 + o * 256 + d] = a;
  scale[512 + o * 256 + 128 + d] = bp[d] - mean * a;
}

// ---------------- stage3: BN-apply + permute + residual relu -----------------------
__global__ __launch_bounds__(256) void k_stage3(
    const u16* __restrict__ y_op, const u16* __restrict__ y_ve,
    const float* __restrict__ scale, const float* __restrict__ gout,
    float* __restrict__ out)
{
  const int stride = gridDim.x * 256;
  const int total = BTOT * 12 * 32;
  for (int id = blockIdx.x * 256 + threadIdx.x; id < total; id += stride) {
    int b = id / 384;
    int rem = id - b * 384;
    int i = rem >> 5;
    int d4 = (rem & 31) * 4;
    int j = c_jmap[i];
    float4 v;
    if (j < 8) {
      ushort4 u = *(const ushort4*)&y_op[((size_t)b * 8 + j) * 128 + d4];
      int o = c_opof[j];
      float4 a4 = *(const float4*)&scale[512 + o * 256 + d4];
      float4 c4 = *(const float4*)&scale[512 + o * 256 + 128 + d4];
      v.x = fmaf(b2f(u.x), a4.x, c4.x);
      v.y = fmaf(b2f(u.y), a4.y, c4.y);
      v.z = fmaf(b2f(u.z), a4.z, c4.z);
      v.w = fmaf(b2f(u.w), a4.w, c4.w);
    } else {
      int jv = c_vj[j - 8];
      ushort4 u = *(const ushort4*)&y_ve[((size_t)b * 12 + jv) * 128 + d4];
      float4 a4 = *(const float4*)&scale[256 + d4];
      float4 c4 = *(const float4*)&scale[384 + d4];
      v.x = fmaxf(fmaf(b2f(u.x), a4.x, c4.x), 0.f);
      v.y = fmaxf(fmaf(b2f(u.y), a4.y, c4.y), 0.f);
      v.z = fmaxf(fmaf(b2f(u.z), a4.z, c4.z), 0.f);
      v.w = fmaxf(fmaf(b2f(u.w), a4.w, c4.w), 0.f);
    }
    float4 g4 = *(const float4*)&gout[((size_t)b * 12 + i) * 128 + d4];
    float4 r4;
    r4.x = fmaxf(g4.x + v.x, 0.f);
    r4.y = fmaxf(g4.y + v.y, 0.f);
    r4.z = fmaxf(g4.z + v.z, 0.f);
    r4.w = fmaxf(g4.w + v.w, 0.f);
    *(float4*)&out[((size_t)b * 12 + i) * 128 + d4] = r4;
  }
}

extern "C" void kernel_launch(void* const* d_in, const int* in_sizes, int n_in,
                              void* d_out, int out_size, void* d_ws, size_t ws_size,
                              hipStream_t stream) {
  (void)in_sizes; (void)n_in; (void)out_size; (void)ws_size;
  const float* gout = (const float*)d_in[0];
  const float* eout = (const float*)d_in[1];
  const float* evs  = (const float*)d_in[2];
  const float* ves  = (const float*)d_in[3];
  const float* wev  = (const float*)d_in[4];
  const float* wve  = (const float*)d_in[5];
  const float* w1   = (const float*)d_in[6];
  const float* w2   = (const float*)d_in[7];
  const float* w3   = (const float*)d_in[8];
  const float* w4   = (const float*)d_in[9];
  const float* g_ev = (const float*)d_in[10]; const float* b_ev = (const float*)d_in[11];
  const float* g_ve = (const float*)d_in[12]; const float* b_ve = (const float*)d_in[13];
  const float* g_1  = (const float*)d_in[14]; const float* b_1  = (const float*)d_in[15];
  const float* g_2  = (const float*)d_in[16]; const float* b_2  = (const float*)d_in[17];
  const float* g_3  = (const float*)d_in[18]; const float* b_3  = (const float*)d_in[19];
  const float* g_4  = (const float*)d_in[20]; const float* b_4  = (const float*)d_in[21];

  char* ws = (char*)d_ws;
  u16*   y_ev  = (u16*)ws;                      // 50,331,648 B
  u16*   y_ve  = (u16*)(ws + 50331648);         // 50,331,648 B
  u16*   y_op  = (u16*)(ws + 100663296);        // 33,554,432 B
  u16*   wb    = (u16*)(ws + 134217728);        // 491,520 B
  float* stats = (float*)(ws + 134709248);      // 16 x 1536 x 4 B = 98,304 B
  float* scale = (float*)(ws + 134807552);      // 6,144 B

  k_prep<<<960, 256, 0, stream>>>(wev, wve, w1, w2, w3, w4, wb, stats);
  k_stage1<<<2048, 256, 0, stream>>>(gout, eout, evs, ves, wb, wb + 32768, y_ev, y_ve, stats);
  k_fin1<<<1, 256, 0, stream>>>(stats, scale, g_ev, b_ev, g_ve, b_ve);
  k_stage2<<<4096, 256, 0, stream>>>(y_ev, y_ve, scale, wb + 65536, wb + 114688, wb + 163840, wb + 196608, y_op, stats);
  k_fin2<<<1, 512, 0, stream>>>(stats, scale, g_1, b_1, g_2, b_2, g_3, b_3, g_4, b_4);
  k_stage3<<<4096, 256, 0, stream>>>(y_op, y_ve, scale, gout, (float*)d_out);
}

// Round 14
// 211.413 us; speedup vs baseline: 1.4334x; 1.4334x over previous
//
#include <hip/hip_runtime.h>
#include <hip/hip_bf16.h>

#define BTOT 16384
typedef unsigned short u16;
typedef __attribute__((ext_vector_type(8))) short bf16x8;
typedef __attribute__((ext_vector_type(8))) unsigned short u16x8;
typedef __attribute__((ext_vector_type(4))) float f32x4;

#define MFMA16(a, b, c) __builtin_amdgcn_mfma_f32_16x16x32_bf16(a, b, c, 0, 0, 0)
#define NSLOT 16

__device__ __forceinline__ u16 f2b(float f) {
  unsigned int i = __float_as_uint(f);
  return (u16)((i + 0x7FFFu + ((i >> 16) & 1u)) >> 16);
}
__device__ __forceinline__ float b2f(u16 u) {
  return __uint_as_float(((unsigned int)u) << 16);
}
__device__ __forceinline__ unsigned pk2(float x, float y) {
  __hip_bfloat162 h = __float22bfloat162_rn(make_float2(x, y));
  unsigned r; __builtin_memcpy(&r, &h, 4); return r;
}
__device__ __forceinline__ bf16x8 pack8(float4 lo, float4 hi) {
  union { unsigned u[4]; bf16x8 v; } r;
  r.u[0] = pk2(lo.x, lo.y); r.u[1] = pk2(lo.z, lo.w);
  r.u[2] = pk2(hi.x, hi.y); r.u[3] = pk2(hi.z, hi.w);
  return r.v;
}

__device__ const int c_mb[8][3]  = {{0,0,0},{1,0,0},{1,0,0},{1,0,0},{1,0,0},{1,0,0},{1,0,0},{1,1,0}};
__device__ const int c_mj[8][3]  = {{0,1,5},{0,3,7},{5,7,8},{1,2,0},{3,4,0},{8,9,0},{10,11,0},{6,7,10}};
__device__ const int c_opof[8]   = {0,1,1,2,2,2,2,3};
__device__ const int c_jmap[12]  = {0,1,3,4,8,9,2,7,5,6,10,11};
__device__ const int c_vj[4]     = {2,4,9,11};

// ---------------- prep: W -> bf16, chunked + pre-swizzled; zero slot-stats ---------
// Per matrix: chunk c (64 k) of 8192 u16; within chunk: d*64 + ((k&63)^((d&7)<<3)).
// W_ve K-halves swapped (k^128) so both stage1 passes use X = [eout | mix].
__global__ __launch_bounds__(256) void k_prep(
    const float* __restrict__ wev, const float* __restrict__ wve,
    const float* __restrict__ w1, const float* __restrict__ w2,
    const float* __restrict__ w3, const float* __restrict__ w4,
    u16* __restrict__ wb, float* __restrict__ stats)
{
  int id = blockIdx.x * 256 + threadIdx.x;
  if (blockIdx.x == 0) {
    for (int i = threadIdx.x; i < NSLOT * 1536; i += 256) stats[i] = 0.f;
  }
  const float* src; int base, K, local;
  if (id < 32768)       { src = wev; base = 0;      K = 256; local = id; }
  else if (id < 65536)  { src = wve; base = 32768;  K = 256; local = id - 32768; }
  else if (id < 114688) { src = w1;  base = 65536;  K = 384; local = id - 65536; }
  else if (id < 163840) { src = w2;  base = 114688; K = 384; local = id - 114688; }
  else if (id < 196608) { src = w3;  base = 163840; K = 256; local = id - 163840; }
  else if (id < 245760) { src = w4;  base = 196608; K = 384; local = id - 196608; }
  else return;
  int d = local / K, k = local - d * K;
  int dk = (base == 32768) ? (k ^ 128) : k;
  int dest = base + (dk >> 6) * 8192 + d * 64 + ((dk & 63) ^ ((d & 7) << 3));
  wb[dest] = f2b(src[local]);
}

// ---------------- stage1: round-10 shape; wload moved AFTER barrier ----------------
// 256 thr = 4 waves (2M x 2N); 8 batches -> M=96, N=128, K=256 per matrix.
__global__ __launch_bounds__(256, 2) void k_stage1(
    const float* __restrict__ gout, const float* __restrict__ eout,
    const float* __restrict__ evs, const float* __restrict__ ves,
    const u16* __restrict__ wb_ev, const u16* __restrict__ wb_ve,
    u16* __restrict__ y_ev, u16* __restrict__ y_ve, float* __restrict__ stats)
{
  __shared__ __align__(16) char lds[81920];
  char* se = lds;                 // 96x128 bf16 eout (swizzled 256B rows); VE dump
  char* sm = lds + 24576;         // mix (ev then ve); EV dump
  char* sw = lds + 49152;         // W double buffer: 2 x 16KB
  float* s_red = (float*)(lds + 49152);  // aliases sw; used only after last W use

  const int tid = threadIdx.x;
  const int l = tid & 63, wv = tid >> 6;
  const int wm = wv >> 1, wn = wv & 1;
  const int b0 = blockIdx.x * 8;
  const int kq = (l >> 4) * 8;
  const int bb = tid >> 5;
  const int d4 = (tid & 31) * 4;

  u16x8 wreg[4];
  auto wload = [&](const u16* wmat, int c) {
    #pragma unroll
    for (int q = 0; q < 4; ++q)
      wreg[q] = *(const u16x8*)&wmat[c * 8192 + tid * 8 + q * 2048];
  };
  auto wstore = [&](char* buf) {
    #pragma unroll
    for (int q = 0; q < 4; ++q)
      *(u16x8*)(buf + (tid * 8 + q * 2048) * 2) = wreg[q];
  };

  wload(wb_ev, 0);   // chunk0 in flight under the prologue

  // ---- fused prologue: stage eout -> se + compute ev mix -> sm ----
  {
    float mev[12][4];
    #pragma unroll
    for (int n = 0; n < 12; ++n)
      #pragma unroll
      for (int q = 0; q < 4; ++q) mev[n][q] = 0.f;
    #pragma unroll
    for (int j = 0; j < 12; ++j) {
      float4 g4 = *(const float4*)&gout[((size_t)(b0 + bb) * 12 + j) * 128 + d4];
      float4 e4 = *(const float4*)&eout[((size_t)(b0 + bb) * 12 + j) * 128 + d4];
      int row = bb * 12 + j;
      uint2 ep = make_uint2(pk2(e4.x, e4.y), pk2(e4.z, e4.w));
      *(uint2*)(se + row * 256 + ((d4 * 2) ^ ((row & 7) << 4))) = ep;
      #pragma unroll
      for (int n = 0; n < 12; ++n) {
        float w = evs[n * 12 + j];   // uniform scalar load (K$)
        mev[n][0] = fmaf(w, g4.x, mev[n][0]); mev[n][1] = fmaf(w, g4.y, mev[n][1]);
        mev[n][2] = fmaf(w, g4.z, mev[n][2]); mev[n][3] = fmaf(w, g4.w, mev[n][3]);
      }
    }
    #pragma unroll
    for (int n = 0; n < 12; ++n) {
      int row = bb * 12 + n;
      uint2 mp = make_uint2(pk2(mev[n][0], mev[n][1]), pk2(mev[n][2], mev[n][3]));
      *(uint2*)(sm + row * 256 + ((d4 * 2) ^ ((row & 7) << 4))) = mp;
    }
  }

  float sE[4] = {0,0,0,0}, qE[4] = {0,0,0,0}, sV[4] = {0,0,0,0}, qV[4] = {0,0,0,0};

  auto run_pass = [&](const u16* wmat, const u16* nextw, u16* yout, char* dump,
                      float* sS, float* qS) {
    f32x4 acc[3][4];
    #pragma unroll
    for (int mi = 0; mi < 3; ++mi)
      #pragma unroll
      for (int ni = 0; ni < 4; ++ni) acc[mi][ni] = (f32x4){0.f, 0.f, 0.f, 0.f};

    wstore(sw);                      // chunk0 -> buf0 (wreg preloaded)
    for (int c = 0; c < 4; ++c) {
      __syncthreads();                         // buf[c&1] ready for all waves
      // FIX (round 12 stall): issue next-chunk loads AFTER the barrier so their
      // latency hides under this phase's MFMA instead of being drained by the
      // barrier's implicit vmcnt(0).
      if (c < 3) wload(wmat, c + 1);
      else if (nextw) wload(nextw, 0);
      const char* xb = (c < 2) ? se : sm;
      const char* swb = sw + ((c & 1) ? 16384 : 0);
      #pragma unroll
      for (int kt = 0; kt < 2; ++kt) {         // 24 MFMA: loads land underneath
        bf16x8 a[3], bq[4];
        const int kb = (((c & 1) * 64 + kt * 32 + kq)) * 2;
        #pragma unroll
        for (int mi = 0; mi < 3; ++mi) {
          int row = (wm * 3 + mi) * 16 + (l & 15);
          a[mi] = *(const bf16x8*)(xb + row * 256 + (kb ^ ((row & 7) << 4)));
        }
        const int kw = (kt * 32 + kq) * 2;
        #pragma unroll
        for (int ni = 0; ni < 4; ++ni) {
          int n = (wn * 4 + ni) * 16 + (l & 15);
          bq[ni] = *(const bf16x8*)(swb + n * 128 + (kw ^ ((n & 7) << 4)));
        }
        #pragma unroll
        for (int mi = 0; mi < 3; ++mi)
          #pragma unroll
          for (int ni = 0; ni < 4; ++ni)
            acc[mi][ni] = MFMA16(a[mi], bq[ni], acc[mi][ni]);
      }
      if (c < 3) wstore(sw + (((c + 1) & 1) ? 16384 : 0));  // write-late into other buf
    }
    __syncthreads();   // all compute done before dump-buffer overwrite
    // epilogue: stats + bf16 dump to LDS + coalesced store
    #pragma unroll
    for (int mi = 0; mi < 3; ++mi)
      #pragma unroll
      for (int ni = 0; ni < 4; ++ni)
        #pragma unroll
        for (int q = 0; q < 4; ++q) {
          float v = acc[mi][ni][q];
          sS[ni] += v; qS[ni] += v * v;
          int row = (wm * 3 + mi) * 16 + (l >> 4) * 4 + q;
          int cb = ((wn * 4 + ni) * 16 + (l & 15)) * 2;
          *(u16*)(dump + row * 256 + (cb ^ ((row & 7) << 4))) = f2b(v);
        }
    __syncthreads();
    #pragma unroll
    for (int q = 0; q < 6; ++q) {
      int i = tid + q * 256;
      int row = i >> 4, cb = (i & 15) * 16;
      u16x8 v = *(const u16x8*)(dump + row * 256 + (cb ^ ((row & 7) << 4)));
      *(u16x8*)&yout[(size_t)(b0 * 12 + row) * 128 + (i & 15) * 8] = v;
    }
    __syncthreads();
  };

  // EV: chunks 0,1 from se, 2,3 from sm(mix_ev); dump into sm (consumed)
  run_pass(wb_ev, wb_ve, y_ev, sm, sE, qE);

  // mix_ve -> sm (gout re-read, L2/L3-hot)
  {
    float mve[12][4];
    #pragma unroll
    for (int n = 0; n < 12; ++n)
      #pragma unroll
      for (int q = 0; q < 4; ++q) mve[n][q] = 0.f;
    #pragma unroll
    for (int j = 0; j < 12; ++j) {
      float4 g4 = *(const float4*)&gout[((size_t)(b0 + bb) * 12 + j) * 128 + d4];
      #pragma unroll
      for (int n = 0; n < 12; ++n) {
        float w = ves[n * 12 + j];   // uniform scalar load
        mve[n][0] = fmaf(w, g4.x, mve[n][0]); mve[n][1] = fmaf(w, g4.y, mve[n][1]);
        mve[n][2] = fmaf(w, g4.z, mve[n][2]); mve[n][3] = fmaf(w, g4.w, mve[n][3]);
      }
    }
    #pragma unroll
    for (int n = 0; n < 12; ++n) {
      int row = bb * 12 + n;
      uint2 mp = make_uint2(pk2(mve[n][0], mve[n][1]), pk2(mve[n][2], mve[n][3]));
      *(uint2*)(sm + row * 256 + ((d4 * 2) ^ ((row & 7) << 4))) = mp;
    }
  }

  // VE: chunks 0,1 from se (W_ve halves pre-swapped), 2,3 from sm(mix_ve); dump se
  run_pass(wb_ve, (const u16*)nullptr, y_ve, se, sV, qV);

  // stats finale: s_red aliases dead W buffer — zero AFTER last W use
  s_red[tid] = 0.f; s_red[tid + 256] = 0.f;
  __syncthreads();
  #pragma unroll
  for (int ni = 0; ni < 4; ++ni) {
    float a1 = sE[ni], b1 = qE[ni], a2 = sV[ni], b2 = qV[ni];
    a1 += __shfl_xor(a1, 16); a1 += __shfl_xor(a1, 32);
    b1 += __shfl_xor(b1, 16); b1 += __shfl_xor(b1, 32);
    a2 += __shfl_xor(a2, 16); a2 += __shfl_xor(a2, 32);
    b2 += __shfl_xor(b2, 16); b2 += __shfl_xor(b2, 32);
    if (l < 16) {
      int ch = (wn * 4 + ni) * 16 + l;
      atomicAdd(&s_red[ch], a1);       atomicAdd(&s_red[128 + ch], b1);
      atomicAdd(&s_red[256 + ch], a2); atomicAdd(&s_red[384 + ch], b2);
    }
  }
  __syncthreads();
  const int sb = (blockIdx.x & (NSLOT - 1)) * 1536;   // slot-spread atomics
  atomicAdd(&stats[sb + tid], s_red[tid]);
  atomicAdd(&stats[sb + 256 + tid], s_red[256 + tid]);
}

// ---------------- fin1: sum slots -> BN affine for ev/ve ---------------------------
__global__ void k_fin1(const float* __restrict__ stats, float* __restrict__ scale,
                       const float* __restrict__ gev, const float* __restrict__ bev,
                       const float* __restrict__ gve, const float* __restrict__ bve)
{
  int t = threadIdx.x;
  int m = t >> 7, d = t & 127;
  float s = 0.f, q = 0.f;
  #pragma unroll
  for (int sl = 0; sl < NSLOT; ++sl) {
    s += stats[sl * 1536 + m * 256 + d];
    q += stats[sl * 1536 + m * 256 + 128 + d];
  }
  float cnt = (float)(BTOT * 12);
  float mean = s / cnt, var = q / cnt - mean * mean;
  float rs = rsqrtf(var + 1e-5f);
  float g = m ? gve[d] : gev[d];
  float b = m ? bve[d] : bev[d];
  float a = g * rs;
  scale[m * 256 + d] = a;
  scale[m * 256 + 128 + d] = b - mean * a;
}

// ---------------- stage2: grouped GEMMs, A direct from global (BN in regs) ---------
// 4096 blocks: r = bid&7, 32 batches; 4 waves (mw x nw); M=32, N=128, K=256/384
__global__ __launch_bounds__(256, 4) void k_stage2(
    const u16* __restrict__ y_ev, const u16* __restrict__ y_ve,
    const float* __restrict__ scale,
    const u16* __restrict__ wb1, const u16* __restrict__ wb2,
    const u16* __restrict__ wb3, const u16* __restrict__ wb4,
    u16* __restrict__ y_op, float* __restrict__ stats)
{
  __shared__ __align__(16) u16 s_w[128 * 64];
  __shared__ __align__(16) u16 s_d[32 * 128];
  __shared__ float s_scale[512];
  __shared__ float s_red[256];
  char* sw = (char*)s_w; char* sd = (char*)s_d;

  const int tid = threadIdx.x, l = tid & 63, wv = tid >> 6;
  const int mw = wv & 1, nw = wv >> 1;
  const int r = blockIdx.x & 7;
  const int b0 = (blockIdx.x >> 3) * 32;
  const int Kr = (r >= 3 && r <= 6) ? 256 : 384;
  const u16* wr = (r == 0) ? wb1 : (r <= 2) ? wb2 : (r <= 6) ? wb3 : wb4;
  const int o = c_opof[r];
  const int j0 = c_mj[r][0], j1 = c_mj[r][1], j2 = c_mj[r][2];
  const int m0 = c_mb[r][0], m1 = c_mb[r][1], m2 = c_mb[r][2];

  for (int i = tid; i < 512; i += 256) s_scale[i] = scale[i];
  s_red[tid] = 0.f;

  f32x4 acc[4];
  #pragma unroll
  for (int ni = 0; ni < 4; ++ni) acc[ni] = (f32x4){0.f, 0.f, 0.f, 0.f};

  const int nch = Kr >> 6;
  const int kq = (l >> 4) * 8;
  const int batch = b0 + mw * 16 + (l & 15);

  for (int c = 0; c < nch; ++c) {
    #pragma unroll
    for (int q = 0; q < 4; ++q) {
      int off = tid * 8 + q * 2048;
      *(u16x8*)(sw + off * 2) = *(const u16x8*)&wr[c * 8192 + off];
    }
    __syncthreads();
    const int s = c >> 1;
    const int j = (s == 0) ? j0 : (s == 1) ? j1 : j2;
    const int mb = (s == 0) ? m0 : (s == 1) ? m1 : m2;
    const int sb = mb ? 256 : 0;
    const u16* ys = mb ? y_ve : y_ev;
    #pragma unroll
    for (int kt = 0; kt < 2; ++kt) {
      const int chan = (c & 1) * 64 + kt * 32 + kq;
      u16x8 u = *(const u16x8*)&ys[((size_t)batch * 12 + j) * 128 + chan];
      float4 a0 = *(const float4*)&s_scale[sb + chan];
      float4 a1 = *(const float4*)&s_scale[sb + chan + 4];
      float4 c0 = *(const float4*)&s_scale[sb + 128 + chan];
      float4 c1 = *(const float4*)&s_scale[sb + 128 + chan + 4];
      float4 lo, hi;
      lo.x = fmaxf(fmaf(b2f(u[0]), a0.x, c0.x), 0.f);
      lo.y = fmaxf(fmaf(b2f(u[1]), a0.y, c0.y), 0.f);
      lo.z = fmaxf(fmaf(b2f(u[2]), a0.z, c0.z), 0.f);
      lo.w = fmaxf(fmaf(b2f(u[3]), a0.w, c0.w), 0.f);
      hi.x = fmaxf(fmaf(b2f(u[4]), a1.x, c1.x), 0.f);
      hi.y = fmaxf(fmaf(b2f(u[5]), a1.y, c1.y), 0.f);
      hi.z = fmaxf(fmaf(b2f(u[6]), a1.z, c1.z), 0.f);
      hi.w = fmaxf(fmaf(b2f(u[7]), a1.w, c1.w), 0.f);
      bf16x8 afrag = pack8(lo, hi);
      const int kw = (kt * 32 + kq) * 2;
      #pragma unroll
      for (int ni = 0; ni < 4; ++ni) {
        int n = (nw * 4 + ni) * 16 + (l & 15);
        bf16x8 b = *(const bf16x8*)(sw + n * 128 + (kw ^ ((n & 7) << 4)));
        acc[ni] = MFMA16(afrag, b, acc[ni]);
      }
    }
    __syncthreads();
  }

  #pragma unroll
  for (int ni = 0; ni < 4; ++ni) {
    float s1 = 0.f, q1 = 0.f;
    #pragma unroll
    for (int q = 0; q < 4; ++q) {
      float v = acc[ni][q];
      s1 += v; q1 += v * v;
      int row = mw * 16 + (l >> 4) * 4 + q;
      int cb = ((nw * 4 + ni) * 16 + (l & 15)) * 2;
      *(u16*)(sd + row * 256 + (cb ^ ((row & 7) << 4))) = f2b(v);
    }
    s1 += __shfl_xor(s1, 16); s1 += __shfl_xor(s1, 32);
    q1 += __shfl_xor(q1, 16); q1 += __shfl_xor(q1, 32);
    if (l < 16) {
      int ch = (nw * 4 + ni) * 16 + l;
      atomicAdd(&s_red[ch], s1);
      atomicAdd(&s_red[128 + ch], q1);
    }
  }
  __syncthreads();
  #pragma unroll
  for (int q = 0; q < 2; ++q) {
    int i = tid + q * 256;
    int row = i >> 4, cb = (i & 15) * 16;
    u16x8 v = *(const u16x8*)(sd + row * 256 + (cb ^ ((row & 7) << 4)));
    *(u16x8*)&y_op[((size_t)(b0 + row) * 8 + r) * 128 + (i & 15) * 8] = v;
  }
  const int sb2 = (blockIdx.x & (NSLOT - 1)) * 1536;
  atomicAdd(&stats[sb2 + 512 + o * 256 + tid], s_red[tid]);
}

// ---------------- fin2: sum slots -> BN affine for ops -----------------------------
__global__ void k_fin2(const float* __restrict__ stats, float* __restrict__ scale,
    const float* __restrict__ g1, const float* __restrict__ b1,
    const float* __restrict__ g2, const float* __restrict__ b2,
    const float* __restrict__ g3, const float* __restrict__ b3,
    const float* __restrict__ g4, const float* __restrict__ b4)
{
  int t = threadIdx.x; // 512
  int o = t >> 7, d = t & 127;
  float s = 0.f, q = 0.f;
  #pragma unroll
  for (int sl = 0; sl < NSLOT; ++sl) {
    s += stats[sl * 1536 + 512 + o * 256 + d];
    q += stats[sl * 1536 + 512 + o * 256 + 128 + d];
  }
  float cnt = (o == 0 || o == 3) ? 16384.f : (o == 1 ? 32768.f : 65536.f);
  float mean = s / cnt, var = q / cnt - mean * mean;
  float rs = rsqrtf(var + 1e-5f);
  const float* gp = (o == 0) ? g1 : (o == 1) ? g2 : (o == 2) ? g3 : g4;
  const float* bp = (o == 0) ? b1 : (o == 1) ? b2 : (o == 2) ? b3 : b4;
  float a = gp[d] * rs;
  scale[512 + o * 256 + d] = a;
  scale[512 + o * 256 + 128 + d] = bp[d] - mean * a;
}

// ---------------- stage3: BN-apply + permute + residual relu -----------------------
__global__ __launch_bounds__(256) void k_stage3(
    const u16* __restrict__ y_op, const u16* __restrict__ y_ve,
    const float* __restrict__ scale, const float* __restrict__ gout,
    float* __restrict__ out)
{
  const int stride = gridDim.x * 256;
  const int total = BTOT * 12 * 32;
  for (int id = blockIdx.x * 256 + threadIdx.x; id < total; id += stride) {
    int b = id / 384;
    int rem = id - b * 384;
    int i = rem >> 5;
    int d4 = (rem & 31) * 4;
    int j = c_jmap[i];
    float4 v;
    if (j < 8) {
      ushort4 u = *(const ushort4*)&y_op[((size_t)b * 8 + j) * 128 + d4];
      int o = c_opof[j];
      float4 a4 = *(const float4*)&scale[512 + o * 256 + d4];
      float4 c4 = *(const float4*)&scale[512 + o * 256 + 128 + d4];
      v.x = fmaf(b2f(u.x), a4.x, c4.x);
      v.y = fmaf(b2f(u.y), a4.y, c4.y);
      v.z = fmaf(b2f(u.z), a4.z, c4.z);
      v.w = fmaf(b2f(u.w), a4.w, c4.w);
    } else {
      int jv = c_vj[j - 8];
      ushort4 u = *(const ushort4*)&y_ve[((size_t)b * 12 + jv) * 128 + d4];
      float4 a4 = *(const float4*)&scale[256 + d4];
      float4 c4 = *(const float4*)&scale[384 + d4];
      v.x = fmaxf(fmaf(b2f(u.x), a4.x, c4.x), 0.f);
      v.y = fmaxf(fmaf(b2f(u.y), a4.y, c4.y), 0.f);
      v.z = fmaxf(fmaf(b2f(u.z), a4.z, c4.z), 0.f);
      v.w = fmaxf(fmaf(b2f(u.w), a4.w, c4.w), 0.f);
    }
    float4 g4 = *(const float4*)&gout[((size_t)b * 12 + i) * 128 + d4];
    float4 r4;
    r4.x = fmaxf(g4.x + v.x, 0.f);
    r4.y = fmaxf(g4.y + v.y, 0.f);
    r4.z = fmaxf(g4.z + v.z, 0.f);
    r4.w = fmaxf(g4.w + v.w, 0.f);
    *(float4*)&out[((size_t)b * 12 + i) * 128 + d4] = r4;
  }
}

extern "C" void kernel_launch(void* const* d_in, const int* in_sizes, int n_in,
                              void* d_out, int out_size, void* d_ws, size_t ws_size,
                              hipStream_t stream) {
  (void)in_sizes; (void)n_in; (void)out_size; (void)ws_size;
  const float* gout = (const float*)d_in[0];
  const float* eout = (const float*)d_in[1];
  const float* evs  = (const float*)d_in[2];
  const float* ves  = (const float*)d_in[3];
  const float* wev  = (const float*)d_in[4];
  const float* wve  = (const float*)d_in[5];
  const float* w1   = (const float*)d_in[6];
  const float* w2   = (const float*)d_in[7];
  const float* w3   = (const float*)d_in[8];
  const float* w4   = (const float*)d_in[9];
  const float* g_ev = (const float*)d_in[10]; const float* b_ev = (const float*)d_in[11];
  const float* g_ve = (const float*)d_in[12]; const float* b_ve = (const float*)d_in[13];
  const float* g_1  = (const float*)d_in[14]; const float* b_1  = (const float*)d_in[15];
  const float* g_2  = (const float*)d_in[16]; const float* b_2  = (const float*)d_in[17];
  const float* g_3  = (const float*)d_in[18]; const float* b_3  = (const float*)d_in[19];
  const float* g_4  = (const float*)d_in[20]; const float* b_4  = (const float*)d_in[21];

  char* ws = (char*)d_ws;
  u16*   y_ev  = (u16*)ws;                      // 50,331,648 B
  u16*   y_ve  = (u16*)(ws + 50331648);         // 50,331,648 B
  u16*   y_op  = (u16*)(ws + 100663296);        // 33,554,432 B
  u16*   wb    = (u16*)(ws + 134217728);        // 491,520 B
  float* stats = (float*)(ws + 134709248);      // 16 x 1536 x 4 B = 98,304 B
  float* scale = (float*)(ws + 134807552);      // 6,144 B

  k_prep<<<960, 256, 0, stream>>>(wev, wve, w1, w2, w3, w4, wb, stats);
  k_stage1<<<2048, 256, 0, stream>>>(gout, eout, evs, ves, wb, wb + 32768, y_ev, y_ve, stats);
  k_fin1<<<1, 256, 0, stream>>>(stats, scale, g_ev, b_ev, g_ve, b_ve);
  k_stage2<<<4096, 256, 0, stream>>>(y_ev, y_ve, scale, wb + 65536, wb + 114688, wb + 163840, wb + 196608, y_op, stats);
  k_fin2<<<1, 512, 0, stream>>>(stats, scale, g_1, b_1, g_2, b_2, g_3, b_3, g_4, b_4);
  k_stage3<<<4096, 256, 0, stream>>>(y_op, y_ve, scale, gout, (float*)d_out);
}

// Round 15
// 207.824 us; speedup vs baseline: 1.4582x; 1.0173x over previous
//
#include <hip/hip_runtime.h>
#include <hip/hip_bf16.h>

#define BTOT 16384
typedef unsigned short u16;
typedef __attribute__((ext_vector_type(8))) short bf16x8;
typedef __attribute__((ext_vector_type(8))) unsigned short u16x8;
typedef __attribute__((ext_vector_type(4))) float f32x4;

#define MFMA16(a, b, c) __builtin_amdgcn_mfma_f32_16x16x32_bf16(a, b, c, 0, 0, 0)
#define NSLOT 16

__device__ __forceinline__ u16 f2b(float f) {
  unsigned int i = __float_as_uint(f);
  return (u16)((i + 0x7FFFu + ((i >> 16) & 1u)) >> 16);
}
__device__ __forceinline__ float b2f(u16 u) {
  return __uint_as_float(((unsigned int)u) << 16);
}
__device__ __forceinline__ unsigned pk2(float x, float y) {
  __hip_bfloat162 h = __float22bfloat162_rn(make_float2(x, y));
  unsigned r; __builtin_memcpy(&r, &h, 4); return r;
}
__device__ __forceinline__ bf16x8 pack8(float4 lo, float4 hi) {
  union { unsigned u[4]; bf16x8 v; } r;
  r.u[0] = pk2(lo.x, lo.y); r.u[1] = pk2(lo.z, lo.w);
  r.u[2] = pk2(hi.x, hi.y); r.u[3] = pk2(hi.z, hi.w);
  return r.v;
}
// async global->LDS DMA, 16B/lane: LDS dest = wave-uniform base + lane*16
__device__ __forceinline__ void glds16(const void* g, void* l) {
  __builtin_amdgcn_global_load_lds(
      (const __attribute__((address_space(1))) void*)g,
      (__attribute__((address_space(3))) void*)l, 16, 0, 0);
}

__device__ const int c_mb[8][3]  = {{0,0,0},{1,0,0},{1,0,0},{1,0,0},{1,0,0},{1,0,0},{1,0,0},{1,1,0}};
__device__ const int c_mj[8][3]  = {{0,1,5},{0,3,7},{5,7,8},{1,2,0},{3,4,0},{8,9,0},{10,11,0},{6,7,10}};
__device__ const int c_opof[8]   = {0,1,1,2,2,2,2,3};
__device__ const int c_jmap[12]  = {0,1,3,4,8,9,2,7,5,6,10,11};
__device__ const int c_vj[4]     = {2,4,9,11};

// ---------------- prep: W -> bf16, chunked + pre-swizzled; zero slot-stats ---------
// Per matrix: chunk c (64 k) of 8192 u16; within chunk: d*64 + ((k&63)^((d&7)<<3)).
// W_ve K-halves swapped (k^128) so both stage1 passes use X = [eout | mix].
__global__ __launch_bounds__(256) void k_prep(
    const float* __restrict__ wev, const float* __restrict__ wve,
    const float* __restrict__ w1, const float* __restrict__ w2,
    const float* __restrict__ w3, const float* __restrict__ w4,
    u16* __restrict__ wb, float* __restrict__ stats)
{
  int id = blockIdx.x * 256 + threadIdx.x;
  if (blockIdx.x == 0) {
    for (int i = threadIdx.x; i < NSLOT * 1536; i += 256) stats[i] = 0.f;
  }
  const float* src; int base, K, local;
  if (id < 32768)       { src = wev; base = 0;      K = 256; local = id; }
  else if (id < 65536)  { src = wve; base = 32768;  K = 256; local = id - 32768; }
  else if (id < 114688) { src = w1;  base = 65536;  K = 384; local = id - 65536; }
  else if (id < 163840) { src = w2;  base = 114688; K = 384; local = id - 114688; }
  else if (id < 196608) { src = w3;  base = 163840; K = 256; local = id - 163840; }
  else if (id < 245760) { src = w4;  base = 196608; K = 384; local = id - 245760 + 49152; }
  else return;
  // (restore correct local for w4)
  if (id >= 196608 && id < 245760) local = id - 196608;
  int d = local / K, k = local - d * K;
  int dk = (base == 32768) ? (k ^ 128) : k;
  int dest = base + (dk >> 6) * 8192 + d * 64 + ((dk & 63) ^ ((d & 7) << 3));
  wb[dest] = f2b(src[local]);
}

// ---------------- stage1: round-10 shape; W staged via global_load_lds DMA ---------
// 256 thr = 4 waves (2M x 2N); 8 batches -> M=96, N=128, K=256 per matrix.
__global__ __launch_bounds__(256, 2) void k_stage1(
    const float* __restrict__ gout, const float* __restrict__ eout,
    const float* __restrict__ evs, const float* __restrict__ ves,
    const u16* __restrict__ wb_ev, const u16* __restrict__ wb_ve,
    u16* __restrict__ y_ev, u16* __restrict__ y_ve, float* __restrict__ stats)
{
  __shared__ __align__(16) char lds[81920];
  char* se = lds;                 // 96x128 bf16 eout (swizzled 256B rows); VE dump
  char* sm = lds + 24576;         // mix (ev then ve); EV dump
  char* sw = lds + 49152;         // W double buffer: 2 x 16KB
  float* s_red = (float*)(lds + 49152);  // aliases sw; used only after last W use

  const int tid = threadIdx.x;
  const int l = tid & 63, wv = tid >> 6;
  const int wm = wv >> 1, wn = wv & 1;
  const int b0 = blockIdx.x * 8;
  const int kq = (l >> 4) * 8;
  const int bb = tid >> 5;
  const int d4 = (tid & 31) * 4;

  // W chunk staging: 4 x 16B DMA per thread; LDS = buf + wv*1024 + q*4096 + lane*16
  auto wstage = [&](const u16* wmat, int c, char* buf) {
    char* wvb = buf + wv * 1024;            // wave-uniform base
    #pragma unroll
    for (int q = 0; q < 4; ++q)
      glds16(&wmat[c * 8192 + tid * 8 + q * 2048], wvb + q * 4096);
  };

  wstage(wb_ev, 0, sw);   // chunk0 DMA in flight under the prologue

  // ---- fused prologue: stage eout -> se + compute ev mix -> sm ----
  {
    float mev[12][4];
    #pragma unroll
    for (int n = 0; n < 12; ++n)
      #pragma unroll
      for (int q = 0; q < 4; ++q) mev[n][q] = 0.f;
    #pragma unroll
    for (int j = 0; j < 12; ++j) {
      float4 g4 = *(const float4*)&gout[((size_t)(b0 + bb) * 12 + j) * 128 + d4];
      float4 e4 = *(const float4*)&eout[((size_t)(b0 + bb) * 12 + j) * 128 + d4];
      int row = bb * 12 + j;
      uint2 ep = make_uint2(pk2(e4.x, e4.y), pk2(e4.z, e4.w));
      *(uint2*)(se + row * 256 + ((d4 * 2) ^ ((row & 7) << 4))) = ep;
      #pragma unroll
      for (int n = 0; n < 12; ++n) {
        float w = evs[n * 12 + j];   // uniform scalar load (K$)
        mev[n][0] = fmaf(w, g4.x, mev[n][0]); mev[n][1] = fmaf(w, g4.y, mev[n][1]);
        mev[n][2] = fmaf(w, g4.z, mev[n][2]); mev[n][3] = fmaf(w, g4.w, mev[n][3]);
      }
    }
    #pragma unroll
    for (int n = 0; n < 12; ++n) {
      int row = bb * 12 + n;
      uint2 mp = make_uint2(pk2(mev[n][0], mev[n][1]), pk2(mev[n][2], mev[n][3]));
      *(uint2*)(sm + row * 256 + ((d4 * 2) ^ ((row & 7) << 4))) = mp;
    }
  }

  float sE[4] = {0,0,0,0}, qE[4] = {0,0,0,0}, sV[4] = {0,0,0,0}, qV[4] = {0,0,0,0};

  auto run_pass = [&](const u16* wmat, const u16* nextw, u16* yout, char* dump,
                      float* sS, float* qS) {
    f32x4 acc[3][4];
    #pragma unroll
    for (int mi = 0; mi < 3; ++mi)
      #pragma unroll
      for (int ni = 0; ni < 4; ++ni) acc[mi][ni] = (f32x4){0.f, 0.f, 0.f, 0.f};

    for (int c = 0; c < 4; ++c) {
      __syncthreads();   // drains buf[c&1]'s DMA; all waves past phase c-1
      // issue next chunk's DMA into the other buffer; completes by next barrier
      if (c < 3) wstage(wmat, c + 1, sw + (((c + 1) & 1) ? 16384 : 0));
      else if (nextw) wstage(nextw, 0, sw);
      const char* xb = (c < 2) ? se : sm;
      const char* swb = sw + ((c & 1) ? 16384 : 0);
      #pragma unroll
      for (int kt = 0; kt < 2; ++kt) {         // 24 MFMA: DMA lands underneath
        bf16x8 a[3], bq[4];
        const int kb = (((c & 1) * 64 + kt * 32 + kq)) * 2;
        #pragma unroll
        for (int mi = 0; mi < 3; ++mi) {
          int row = (wm * 3 + mi) * 16 + (l & 15);
          a[mi] = *(const bf16x8*)(xb + row * 256 + (kb ^ ((row & 7) << 4)));
        }
        const int kw = (kt * 32 + kq) * 2;
        #pragma unroll
        for (int ni = 0; ni < 4; ++ni) {
          int n = (wn * 4 + ni) * 16 + (l & 15);
          bq[ni] = *(const bf16x8*)(swb + n * 128 + (kw ^ ((n & 7) << 4)));
        }
        #pragma unroll
        for (int mi = 0; mi < 3; ++mi)
          #pragma unroll
          for (int ni = 0; ni < 4; ++ni)
            acc[mi][ni] = MFMA16(a[mi], bq[ni], acc[mi][ni]);
      }
    }
    __syncthreads();   // all compute done before dump-buffer overwrite
    // epilogue: stats + bf16 dump to LDS + coalesced store
    #pragma unroll
    for (int mi = 0; mi < 3; ++mi)
      #pragma unroll
      for (int ni = 0; ni < 4; ++ni)
        #pragma unroll
        for (int q = 0; q < 4; ++q) {
          float v = acc[mi][ni][q];
          sS[ni] += v; qS[ni] += v * v;
          int row = (wm * 3 + mi) * 16 + (l >> 4) * 4 + q;
          int cb = ((wn * 4 + ni) * 16 + (l & 15)) * 2;
          *(u16*)(dump + row * 256 + (cb ^ ((row & 7) << 4))) = f2b(v);
        }
    __syncthreads();
    #pragma unroll
    for (int q = 0; q < 6; ++q) {
      int i = tid + q * 256;
      int row = i >> 4, cb = (i & 15) * 16;
      u16x8 v = *(const u16x8*)(dump + row * 256 + (cb ^ ((row & 7) << 4)));
      *(u16x8*)&yout[(size_t)(b0 * 12 + row) * 128 + (i & 15) * 8] = v;
    }
    __syncthreads();
  };

  // EV: chunks 0,1 from se, 2,3 from sm(mix_ev); dump into sm (consumed)
  run_pass(wb_ev, wb_ve, y_ev, sm, sE, qE);

  // mix_ve -> sm (gout re-read, L2/L3-hot)
  {
    float mve[12][4];
    #pragma unroll
    for (int n = 0; n < 12; ++n)
      #pragma unroll
      for (int q = 0; q < 4; ++q) mve[n][q] = 0.f;
    #pragma unroll
    for (int j = 0; j < 12; ++j) {
      float4 g4 = *(const float4*)&gout[((size_t)(b0 + bb) * 12 + j) * 128 + d4];
      #pragma unroll
      for (int n = 0; n < 12; ++n) {
        float w = ves[n * 12 + j];   // uniform scalar load
        mve[n][0] = fmaf(w, g4.x, mve[n][0]); mve[n][1] = fmaf(w, g4.y, mve[n][1]);
        mve[n][2] = fmaf(w, g4.z, mve[n][2]); mve[n][3] = fmaf(w, g4.w, mve[n][3]);
      }
    }
    #pragma unroll
    for (int n = 0; n < 12; ++n) {
      int row = bb * 12 + n;
      uint2 mp = make_uint2(pk2(mve[n][0], mve[n][1]), pk2(mve[n][2], mve[n][3]));
      *(uint2*)(sm + row * 256 + ((d4 * 2) ^ ((row & 7) << 4))) = mp;
    }
  }

  // VE: chunks 0,1 from se (W_ve halves pre-swapped), 2,3 from sm(mix_ve); dump se
  run_pass(wb_ve, (const u16*)nullptr, y_ve, se, sV, qV);

  // stats finale: s_red aliases dead W buffer — zero AFTER last W use
  s_red[tid] = 0.f; s_red[tid + 256] = 0.f;
  __syncthreads();
  #pragma unroll
  for (int ni = 0; ni < 4; ++ni) {
    float a1 = sE[ni], b1 = qE[ni], a2 = sV[ni], b2 = qV[ni];
    a1 += __shfl_xor(a1, 16); a1 += __shfl_xor(a1, 32);
    b1 += __shfl_xor(b1, 16); b1 += __shfl_xor(b1, 32);
    a2 += __shfl_xor(a2, 16); a2 += __shfl_xor(a2, 32);
    b2 += __shfl_xor(b2, 16); b2 += __shfl_xor(b2, 32);
    if (l < 16) {
      int ch = (wn * 4 + ni) * 16 + l;
      atomicAdd(&s_red[ch], a1);       atomicAdd(&s_red[128 + ch], b1);
      atomicAdd(&s_red[256 + ch], a2); atomicAdd(&s_red[384 + ch], b2);
    }
  }
  __syncthreads();
  const int sb = (blockIdx.x & (NSLOT - 1)) * 1536;   // slot-spread atomics
  atomicAdd(&stats[sb + tid], s_red[tid]);
  atomicAdd(&stats[sb + 256 + tid], s_red[256 + tid]);
}

// ---------------- fin1: sum slots -> BN affine for ev/ve ---------------------------
__global__ void k_fin1(const float* __restrict__ stats, float* __restrict__ scale,
                       const float* __restrict__ gev, const float* __restrict__ bev,
                       const float* __restrict__ gve, const float* __restrict__ bve)
{
  int t = threadIdx.x;
  int m = t >> 7, d = t & 127;
  float s = 0.f, q = 0.f;
  #pragma unroll
  for (int sl = 0; sl < NSLOT; ++sl) {
    s += stats[sl * 1536 + m * 256 + d];
    q += stats[sl * 1536 + m * 256 + 128 + d];
  }
  float cnt = (float)(BTOT * 12);
  float mean = s / cnt, var = q / cnt - mean * mean;
  float rs = rsqrtf(var + 1e-5f);
  float g = m ? gve[d] : gev[d];
  float b = m ? bve[d] : bev[d];
  float a = g * rs;
  scale[m * 256 + d] = a;
  scale[m * 256 + 128 + d] = b - mean * a;
}

// ---------------- stage2: grouped GEMMs; W staged via global_load_lds DMA ----------
// 4096 blocks: r = bid&7, 32 batches; 4 waves (mw x nw); M=32, N=128, K=256/384
__global__ __launch_bounds__(256, 4) void k_stage2(
    const u16* __restrict__ y_ev, const u16* __restrict__ y_ve,
    const float* __restrict__ scale,
    const u16* __restrict__ wb1, const u16* __restrict__ wb2,
    const u16* __restrict__ wb3, const u16* __restrict__ wb4,
    u16* __restrict__ y_op, float* __restrict__ stats)
{
  __shared__ __align__(16) u16 s_w[128 * 64];
  __shared__ __align__(16) u16 s_d[32 * 128];
  __shared__ float s_scale[512];
  __shared__ float s_red[256];
  char* sw = (char*)s_w; char* sd = (char*)s_d;

  const int tid = threadIdx.x, l = tid & 63, wv = tid >> 6;
  const int mw = wv & 1, nw = wv >> 1;
  const int r = blockIdx.x & 7;
  const int b0 = (blockIdx.x >> 3) * 32;
  const int Kr = (r >= 3 && r <= 6) ? 256 : 384;
  const u16* wr = (r == 0) ? wb1 : (r <= 2) ? wb2 : (r <= 6) ? wb3 : wb4;
  const int o = c_opof[r];
  const int j0 = c_mj[r][0], j1 = c_mj[r][1], j2 = c_mj[r][2];
  const int m0 = c_mb[r][0], m1 = c_mb[r][1], m2 = c_mb[r][2];

  for (int i = tid; i < 512; i += 256) s_scale[i] = scale[i];
  s_red[tid] = 0.f;

  f32x4 acc[4];
  #pragma unroll
  for (int ni = 0; ni < 4; ++ni) acc[ni] = (f32x4){0.f, 0.f, 0.f, 0.f};

  const int nch = Kr >> 6;
  const int kq = (l >> 4) * 8;
  const int batch = b0 + mw * 16 + (l & 15);

  for (int c = 0; c < nch; ++c) {
    {
      char* wvb = sw + wv * 1024;   // wave-uniform LDS base; DMA adds lane*16
      #pragma unroll
      for (int q = 0; q < 4; ++q)
        glds16(&wr[c * 8192 + tid * 8 + q * 2048], wvb + q * 4096);
    }
    __syncthreads();
    const int s = c >> 1;
    const int j = (s == 0) ? j0 : (s == 1) ? j1 : j2;
    const int mb = (s == 0) ? m0 : (s == 1) ? m1 : m2;
    const int sb = mb ? 256 : 0;
    const u16* ys = mb ? y_ve : y_ev;
    #pragma unroll
    for (int kt = 0; kt < 2; ++kt) {
      const int chan = (c & 1) * 64 + kt * 32 + kq;
      u16x8 u = *(const u16x8*)&ys[((size_t)batch * 12 + j) * 128 + chan];
      float4 a0 = *(const float4*)&s_scale[sb + chan];
      float4 a1 = *(const float4*)&s_scale[sb + chan + 4];
      float4 c0 = *(const float4*)&s_scale[sb + 128 + chan];
      float4 c1 = *(const float4*)&s_scale[sb + 128 + chan + 4];
      float4 lo, hi;
      lo.x = fmaxf(fmaf(b2f(u[0]), a0.x, c0.x), 0.f);
      lo.y = fmaxf(fmaf(b2f(u[1]), a0.y, c0.y), 0.f);
      lo.z = fmaxf(fmaf(b2f(u[2]), a0.z, c0.z), 0.f);
      lo.w = fmaxf(fmaf(b2f(u[3]), a0.w, c0.w), 0.f);
      hi.x = fmaxf(fmaf(b2f(u[4]), a1.x, c1.x), 0.f);
      hi.y = fmaxf(fmaf(b2f(u[5]), a1.y, c1.y), 0.f);
      hi.z = fmaxf(fmaf(b2f(u[6]), a1.z, c1.z), 0.f);
      hi.w = fmaxf(fmaf(b2f(u[7]), a1.w, c1.w), 0.f);
      bf16x8 afrag = pack8(lo, hi);
      const int kw = (kt * 32 + kq) * 2;
      #pragma unroll
      for (int ni = 0; ni < 4; ++ni) {
        int n = (nw * 4 + ni) * 16 + (l & 15);
        bf16x8 b = *(const bf16x8*)(sw + n * 128 + (kw ^ ((n & 7) << 4)));
        acc[ni] = MFMA16(afrag, b, acc[ni]);
      }
    }
    __syncthreads();
  }

  #pragma unroll
  for (int ni = 0; ni < 4; ++ni) {
    float s1 = 0.f, q1 = 0.f;
    #pragma unroll
    for (int q = 0; q < 4; ++q) {
      float v = acc[ni][q];
      s1 += v; q1 += v * v;
      int row = mw * 16 + (l >> 4) * 4 + q;
      int cb = ((nw * 4 + ni) * 16 + (l & 15)) * 2;
      *(u16*)(sd + row * 256 + (cb ^ ((row & 7) << 4))) = f2b(v);
    }
    s1 += __shfl_xor(s1, 16); s1 += __shfl_xor(s1, 32);
    q1 += __shfl_xor(q1, 16); q1 += __shfl_xor(q1, 32);
    if (l < 16) {
      int ch = (nw * 4 + ni) * 16 + l;
      atomicAdd(&s_red[ch], s1);
      atomicAdd(&s_red[128 + ch], q1);
    }
  }
  __syncthreads();
  #pragma unroll
  for (int q = 0; q < 2; ++q) {
    int i = tid + q * 256;
    int row = i >> 4, cb = (i & 15) * 16;
    u16x8 v = *(const u16x8*)(sd + row * 256 + (cb ^ ((row & 7) << 4)));
    *(u16x8*)&y_op[((size_t)(b0 + row) * 8 + r) * 128 + (i & 15) * 8] = v;
  }
  const int sb2 = (blockIdx.x & (NSLOT - 1)) * 1536;
  atomicAdd(&stats[sb2 + 512 + o * 256 + tid], s_red[tid]);
}

// ---------------- fin2: sum slots -> BN affine for ops -----------------------------
__global__ void k_fin2(const float* __restrict__ stats, float* __restrict__ scale,
    const float* __restrict__ g1, const float* __restrict__ b1,
    const float* __restrict__ g2, const float* __restrict__ b2,
    const float* __restrict__ g3, const float* __restrict__ b3,
    const float* __restrict__ g4, const float* __restrict__ b4)
{
  int t = threadIdx.x; // 512
  int o = t >> 7, d = t & 127;
  float s = 0.f, q = 0.f;
  #pragma unroll
  for (int sl = 0; sl < NSLOT; ++sl) {
    s += stats[sl * 1536 + 512 + o * 256 + d];
    q += stats[sl * 1536 + 512 + o * 256 + 128 + d];
  }
  float cnt = (o == 0 || o == 3) ? 16384.f : (o == 1 ? 32768.f : 65536.f);
  float mean = s / cnt, var = q / cnt - mean * mean;
  float rs = rsqrtf(var + 1e-5f);
  const float* gp = (o == 0) ? g1 : (o == 1) ? g2 : (o == 2) ? g3 : g4;
  const float* bp = (o == 0) ? b1 : (o == 1) ? b2 : (o == 2) ? b3 : b4;
  float a = gp[d] * rs;
  scale[512 + o * 256 + d] = a;
  scale[512 + o * 256 + 128 + d] = bp[d] - mean * a;
}

// ---------------- stage3: BN-apply + permute + residual relu -----------------------
__global__ __launch_bounds__(256) void k_stage3(
    const u16* __restrict__ y_op, const u16* __restrict__ y_ve,
    const float* __restrict__ scale, const float* __restrict__ gout,
    float* __restrict__ out)
{
  const int stride = gridDim.x * 256;
  const int total = BTOT * 12 * 32;
  for (int id = blockIdx.x * 256 + threadIdx.x; id < total; id += stride) {
    int b = id / 384;
    int rem = id - b * 384;
    int i = rem >> 5;
    int d4 = (rem & 31) * 4;
    int j = c_jmap[i];
    float4 v;
    if (j < 8) {
      ushort4 u = *(const ushort4*)&y_op[((size_t)b * 8 + j) * 128 + d4];
      int o = c_opof[j];
      float4 a4 = *(const float4*)&scale[512 + o * 256 + d4];
      float4 c4 = *(const float4*)&scale[512 + o * 256 + 128 + d4];
      v.x = fmaf(b2f(u.x), a4.x, c4.x);
      v.y = fmaf(b2f(u.y), a4.y, c4.y);
      v.z = fmaf(b2f(u.z), a4.z, c4.z);
      v.w = fmaf(b2f(u.w), a4.w, c4.w);
    } else {
      int jv = c_vj[j - 8];
      ushort4 u = *(const ushort4*)&y_ve[((size_t)b * 12 + jv) * 128 + d4];
      float4 a4 = *(const float4*)&scale[256 + d4];
      float4 c4 = *(const float4*)&scale[384 + d4];
      v.x = fmaxf(fmaf(b2f(u.x), a4.x, c4.x), 0.f);
      v.y = fmaxf(fmaf(b2f(u.y), a4.y, c4.y), 0.f);
      v.z = fmaxf(fmaf(b2f(u.z), a4.z, c4.z), 0.f);
      v.w = fmaxf(fmaf(b2f(u.w), a4.w, c4.w), 0.f);
    }
    float4 g4 = *(const float4*)&gout[((size_t)b * 12 + i) * 128 + d4];
    float4 r4;
    r4.x = fmaxf(g4.x + v.x, 0.f);
    r4.y = fmaxf(g4.y + v.y, 0.f);
    r4.z = fmaxf(g4.z + v.z, 0.f);
    r4.w = fmaxf(g4.w + v.w, 0.f);
    *(float4*)&out[((size_t)b * 12 + i) * 128 + d4] = r4;
  }
}

extern "C" void kernel_launch(void* const* d_in, const int* in_sizes, int n_in,
                              void* d_out, int out_size, void* d_ws, size_t ws_size,
                              hipStream_t stream) {
  (void)in_sizes; (void)n_in; (void)out_size; (void)ws_size;
  const float* gout = (const float*)d_in[0];
  const float* eout = (const float*)d_in[1];
  const float* evs  = (const float*)d_in[2];
  const float* ves  = (const float*)d_in[3];
  const float* wev  = (const float*)d_in[4];
  const float* wve  = (const float*)d_in[5];
  const float* w1   = (const float*)d_in[6];
  const float* w2   = (const float*)d_in[7];
  const float* w3   = (const float*)d_in[8];
  const float* w4   = (const float*)d_in[9];
  const float* g_ev = (const float*)d_in[10]; const float* b_ev = (const float*)d_in[11];
  const float* g_ve = (const float*)d_in[12]; const float* b_ve = (const float*)d_in[13];
  const float* g_1  = (const float*)d_in[14]; const float* b_1  = (const float*)d_in[15];
  const float* g_2  = (const float*)d_in[16]; const float* b_2  = (const float*)d_in[17];
  const float* g_3  = (const float*)d_in[18]; const float* b_3  = (const float*)d_in[19];
  const float* g_4  = (const float*)d_in[20]; const float* b_4  = (const float*)d_in[21];

  char* ws = (char*)d_ws;
  u16*   y_ev  = (u16*)ws;                      // 50,331,648 B
  u16*   y_ve  = (u16*)(ws + 50331648);         // 50,331,648 B
  u16*   y_op  = (u16*)(ws + 100663296);        // 33,554,432 B
  u16*   wb    = (u16*)(ws + 134217728);        // 491,520 B
  float* stats = (float*)(ws + 134709248);      // 16 x 1536 x 4 B = 98,304 B
  float* scale = (float*)(ws + 134807552);      // 6,144 B

  k_prep<<<960, 256, 0, stream>>>(wev, wve, w1, w2, w3, w4, wb, stats);
  k_stage1<<<2048, 256, 0, stream>>>(gout, eout, evs, ves, wb, wb + 32768, y_ev, y_ve, stats);
  k_fin1<<<1, 256, 0, stream>>>(stats, scale, g_ev, b_ev, g_ve, b_ve);
  k_stage2<<<4096, 256, 0, stream>>>(y_ev, y_ve, scale, wb + 65536, wb + 114688, wb + 163840, wb + 196608, y_op, stats);
  k_fin2<<<1, 512, 0, stream>>>(stats, scale, g_1, b_1, g_2, b_2, g_3, b_3, g_4, b_4);
  k_stage3<<<4096, 256, 0, stream>>>(y_op, y_ve, scale, gout, (float*)d_out);
}